// Round 1
// 482.817 us; speedup vs baseline: 1.0055x; 1.0055x over previous
//
#include <hip/hip_runtime.h>

constexpr int DIM     = 128;
constexpr int BS      = 512;
constexpr int POS_K   = 32;
constexpr int NUM_NEG = 1024;
constexpr float INV_TEMP = 1.0f / 0.07f;

// flat output offsets, in return order
constexpr long long OFF_V2A_POS = 0;
constexpr long long OFF_V2A_NEG = OFF_V2A_POS + BS;                         // 512
constexpr long long OFF_A2V_POS = OFF_V2A_NEG + (long long)BS * NUM_NEG;    // 524800
constexpr long long OFF_A2V_NEG = OFF_A2V_POS + BS;                         // 525312
constexpr long long OFF_VV_POS  = OFF_A2V_NEG + (long long)BS * NUM_NEG;    // 1049600
constexpr long long OFF_VV_NEG  = OFF_VV_POS  + (long long)BS * POS_K;      // 1065984
constexpr long long OFF_AA_POS  = OFF_VV_NEG  + (long long)BS * NUM_NEG;    // 1590272
constexpr long long OFF_AA_NEG  = OFF_AA_POS  + (long long)BS * POS_K;      // 1606656

__device__ __forceinline__ float dot4(const float4 a, const float4 b) {
    return fmaf(a.x, b.x, fmaf(a.y, b.y, fmaf(a.z, b.z, a.w * b.w)));
}

// Block layout: gridDim.x = BS*2. Block (b, h): b = bid>>1 handles batch row b,
// half h = bid&1 handles negatives [h*512, h*512+512) and positives [h*16, h*16+16).
// 512 threads = 8 waves. Each wave-iteration: 32 lanes per gathered row
// (float4/lane = 512 B coalesced row read), 2 rows per wave (lane group g = l>>5).
//
// PHASE SPLIT (this round's change): all mem1 gathers happen before any mem2
// gather. Per-phase distinct-row footprint ~166 MB fits the 256 MiB L3, so the
// ~38% birthday-repeat gathers across blocks become L3 hits instead of HBM
// fetches. Interleaved mem1+mem2 (previous version) had a 512 MB combined
// footprint that thrashed L3.
__global__ __launch_bounds__(512) void avid_cma_kernel(
    const float* __restrict__ video, const float* __restrict__ audio,
    const float* __restrict__ mem1,  const float* __restrict__ mem2,
    const int* __restrict__ y, const int* __restrict__ pos_idx,
    const int* __restrict__ neg_idx, float* __restrict__ out)
{
    const int tid  = threadIdx.x;
    const int h    = blockIdx.x & 1;
    const int b    = blockIdx.x >> 1;
    const int wave = tid >> 6;
    const int l    = tid & 63;
    const int g    = l >> 5;   // which of the 2 rows this half-wave handles
    const int li   = l & 31;   // lane within the 32-lane row group

    __shared__ int s_nidx[512];
    __shared__ int s_pidx[16];

    s_nidx[tid] = neg_idx[b * NUM_NEG + h * 512 + tid];
    if (tid < 16) s_pidx[tid] = pos_idx[b * POS_K + h * 16 + tid];

    // ctx slices: lane li owns elements [4*li, 4*li+4) of v and a (raw, unnormalized)
    const float4 vt = *(const float4*)(video + b * DIM + li * 4);
    const float4 at = *(const float4*)(audio + b * DIM + li * 4);

    // norms: each 32-lane half covers all 128 elements -> butterfly within half
    float ssv = dot4(vt, vt);
    float ssa = dot4(at, at);
#pragma unroll
    for (int m = 16; m >= 1; m >>= 1) {
        ssv += __shfl_xor(ssv, m, 64);
        ssa += __shfl_xor(ssa, m, 64);
    }
    const float sc_v = INV_TEMP / fmaxf(sqrtf(ssv), 1e-12f);
    const float sc_a = INV_TEMP / fmaxf(sqrtf(ssa), 1e-12f);

    __syncthreads();

    // ---------------- Phase 1: mem1 (view1) gathers only ----------------
    {
        float* o_vv_neg  = out + OFF_VV_NEG  + (long long)b * NUM_NEG + h * 512;
        float* o_a2v_neg = out + OFF_A2V_NEG + (long long)b * NUM_NEG + h * 512;

#pragma unroll 4
        for (int j = wave * 2; j < 512; j += 16) {
            const int idx = s_nidx[j + g];
            const float4 m1 = *(const float4*)(mem1 + (size_t)idx * DIM + li * 4);
            float dv = dot4(m1, vt);   // pos_v2v_neg
            float da = dot4(m1, at);   // inst_a2v_neg
#pragma unroll
            for (int m = 16; m >= 1; m >>= 1) {
                dv += __shfl_xor(dv, m, 64);
                da += __shfl_xor(da, m, 64);
            }
            if (li == 0) {
                o_vv_neg [j + g] = dv * sc_v;
                o_a2v_neg[j + g] = da * sc_a;
            }
        }

        // positives from mem1: pos_v2v_pos (one iteration per wave)
        {
            const int j = wave * 2;
            const int idx = s_pidx[j + g];
            const float4 p1 = *(const float4*)(mem1 + (size_t)idx * DIM + li * 4);
            float d = dot4(p1, vt);
#pragma unroll
            for (int m = 16; m >= 1; m >>= 1) d += __shfl_xor(d, m, 64);
            if (li == 0)
                out[OFF_VV_POS + (long long)b * POS_K + h * 16 + j + g] = d * sc_v;
        }

        // self from mem1: inst_a2v_pos = (mem1[y]·a) * sc_a
        if (h == 0 && wave == 0 && g == 0) {
            const int idx = y[b];
            const float4 s = *(const float4*)(mem1 + (size_t)idx * DIM + li * 4);
            float d = dot4(s, at);
#pragma unroll
            for (int m = 16; m >= 1; m >>= 1) d += __shfl_xor(d, m, 64);
            if (li == 0) out[OFF_A2V_POS + b] = d * sc_a;
        }
    }

    __syncthreads();   // keep the block's waves phase-coherent

    // ---------------- Phase 2: mem2 (view2) gathers only ----------------
    {
        float* o_v2a_neg = out + OFF_V2A_NEG + (long long)b * NUM_NEG + h * 512;
        float* o_aa_neg  = out + OFF_AA_NEG  + (long long)b * NUM_NEG + h * 512;

#pragma unroll 4
        for (int j = wave * 2; j < 512; j += 16) {
            const int idx = s_nidx[j + g];
            const float4 m2 = *(const float4*)(mem2 + (size_t)idx * DIM + li * 4);
            float dv = dot4(m2, vt);   // inst_v2a_neg
            float da = dot4(m2, at);   // pos_a2a_neg
#pragma unroll
            for (int m = 16; m >= 1; m >>= 1) {
                dv += __shfl_xor(dv, m, 64);
                da += __shfl_xor(da, m, 64);
            }
            if (li == 0) {
                o_v2a_neg[j + g] = dv * sc_v;
                o_aa_neg [j + g] = da * sc_a;
            }
        }

        // positives from mem2: pos_a2a_pos
        {
            const int j = wave * 2;
            const int idx = s_pidx[j + g];
            const float4 p2 = *(const float4*)(mem2 + (size_t)idx * DIM + li * 4);
            float d = dot4(p2, at);
#pragma unroll
            for (int m = 16; m >= 1; m >>= 1) d += __shfl_xor(d, m, 64);
            if (li == 0)
                out[OFF_AA_POS + (long long)b * POS_K + h * 16 + j + g] = d * sc_a;
        }

        // self from mem2: inst_v2a_pos = (mem2[y]·v) * sc_v
        if (h == 0 && wave == 0 && g == 0) {
            const int idx = y[b];
            const float4 s = *(const float4*)(mem2 + (size_t)idx * DIM + li * 4);
            float d = dot4(s, vt);
#pragma unroll
            for (int m = 16; m >= 1; m >>= 1) d += __shfl_xor(d, m, 64);
            if (li == 0) out[OFF_V2A_POS + b] = d * sc_v;
        }
    }
}

extern "C" void kernel_launch(void* const* d_in, const int* in_sizes, int n_in,
                              void* d_out, int out_size, void* d_ws, size_t ws_size,
                              hipStream_t stream) {
    const float* video   = (const float*)d_in[0];
    const float* audio   = (const float*)d_in[1];
    const float* mem1    = (const float*)d_in[2];
    const float* mem2    = (const float*)d_in[3];
    const int*   y       = (const int*)d_in[4];
    const int*   pos_idx = (const int*)d_in[5];
    const int*   neg_idx = (const int*)d_in[6];
    float*       out     = (float*)d_out;

    avid_cma_kernel<<<dim3(BS * 2), dim3(512), 0, stream>>>(
        video, audio, mem1, mem2, y, pos_idx, neg_idx, out);
}